// Round 1
// baseline (189.647 us; speedup 1.0000x reference)
//
#include <hip/hip_runtime.h>
#include <hip/hip_bf16.h>
#include <stdint.h>

// KipfMLPGNN: B=32 batches, N=64 nodes, D=128 embd, H=256 hidden, L=3 layers.
// Key factorization: first MLP layer split into per-node sender/receiver halves.

#define NB 32
#define NN 64
#define DD 128
#define HH 256

typedef __attribute__((ext_vector_type(4))) float f32x4;
typedef __attribute__((ext_vector_type(8))) __bf16 bf16x8;

__device__ __forceinline__ uint16_t f2bf(float x) {
  uint32_t u = __builtin_bit_cast(uint32_t, x);
  u += 0x7fffu + ((u >> 16) & 1u);   // RNE
  return (uint16_t)(u >> 16);
}

// E[node][d] = table[x[node]][d]    (2048 nodes x 128 f32, via float4)
__global__ __launch_bounds__(256) void k_gather(const int* __restrict__ x,
                                                const float* __restrict__ table,
                                                float* __restrict__ E) {
  int i = blockIdx.x * 256 + threadIdx.x;     // 0..65535 float4 slots
  int node = i >> 5;
  ((f32x4*)E)[i] = ((const f32x4*)table)[(size_t)x[node] * 32 + (i & 31)];
}

// Wt[g][k][h]: g0=W1_0 sender half, g1=W1_0 receiver half, g2/g3 = W1_1 halves
// (transposed to [k][h] so k_T's weight loads coalesce).
// W2bf[2][d][h]: bf16 copies of W2_0 / W2_1 (row-major, h contiguous).
__global__ __launch_bounds__(256) void k_prep(const float* __restrict__ W1_0,
                                              const float* __restrict__ W1_1,
                                              const float* __restrict__ W2_0,
                                              const float* __restrict__ W2_1,
                                              float* __restrict__ Wt,
                                              uint16_t* __restrict__ W2bf) {
  int tid = blockIdx.x * 256 + threadIdx.x;   // 65536 threads
  for (int idx = tid; idx < 4 * 128 * 256; idx += 65536) {
    int g = idx >> 15, k = (idx >> 8) & 127, h = idx & 255;
    const float* W = (g < 2) ? W1_0 : W1_1;
    Wt[idx] = W[h * 256 + (g & 1) * 128 + k];
  }
  if (tid < 32768) {
    W2bf[tid]         = f2bf(W2_0[tid]);
    W2bf[32768 + tid] = f2bf(W2_1[tid]);
  }
}

// Tall[node][1024] = [Ts0 | Tr0+b1_0 | Ts1 | Tr1+b1_1]   (f32, per layer)
// Block: 8 nodes, 256 threads; thread t owns column h=t of all 4 groups.
__global__ __launch_bounds__(256) void k_T(const float* __restrict__ E,
                                           const float* __restrict__ Wt,
                                           const float* __restrict__ b1_0,
                                           const float* __restrict__ b1_1,
                                           float* __restrict__ Tall) {
  __shared__ float Els[8 * 128];
  int t = threadIdx.x;
  int node0 = blockIdx.x * 8;
  ((f32x4*)Els)[t] = ((const f32x4*)(E + (size_t)node0 * 128))[t];
  __syncthreads();
  float acc[4][8];
#pragma unroll
  for (int g = 0; g < 4; ++g)
#pragma unroll
    for (int m = 0; m < 8; ++m) acc[g][m] = 0.f;
#pragma unroll 4
  for (int k = 0; k < 128; ++k) {
    float w0 = Wt[(0 * 128 + k) * 256 + t];
    float w1 = Wt[(1 * 128 + k) * 256 + t];
    float w2 = Wt[(2 * 128 + k) * 256 + t];
    float w3 = Wt[(3 * 128 + k) * 256 + t];
#pragma unroll
    for (int m = 0; m < 8; ++m) {
      float e = Els[m * 128 + k];      // broadcast read
      acc[0][m] = fmaf(e, w0, acc[0][m]);
      acc[1][m] = fmaf(e, w1, acc[1][m]);
      acc[2][m] = fmaf(e, w2, acc[2][m]);
      acc[3][m] = fmaf(e, w3, acc[3][m]);
    }
  }
  float bias1 = b1_0[t], bias3 = b1_1[t];
#pragma unroll
  for (int m = 0; m < 8; ++m) {
    float* row = Tall + (size_t)(node0 + m) * 1024;
    row[0 * 256 + t] = acc[0][m];
    row[1 * 256 + t] = acc[1][m] + bias1;
    row[2 * 256 + t] = acc[2][m];
    row[3 * 256 + t] = acc[3][m] + bias3;
  }
}

// One block per (b, r): h{0,1}[c][k] = relu(Ts[c][k] + Tr[r][k]) staged to LDS
// as bf16 (XOR swizzle byte ^= (c&7)<<4 kills the 512B-stride bank conflict),
// then 64x256 @ 256x128 MFMA for both MLPs, epilogue blends by arc and
// reduces over c. last=1: r=0 only, write d_out[b][d] = E[b][0][d] + agg.
__global__ __launch_bounds__(256) void k_edge(const float* __restrict__ Tall,
                                              const int* __restrict__ arcs,
                                              const float* E,
                                              float* out,
                                              const uint16_t* __restrict__ W2bf,
                                              const float* __restrict__ b2_0,
                                              const float* __restrict__ b2_1,
                                              int last) {
  __shared__ uint16_t hl[2][NN * HH];   // 2 x 32 KB
  int t = threadIdx.x;
  int b = blockIdx.y;
  int r = last ? 0 : blockIdx.x;
  const float* Tb = Tall + (size_t)b * NN * 1024;

  {  // staging: thread t owns row c=t>>2, quarter (t&3); 16 float4 steps
    int c = t >> 2;
    int kq = (t & 3) * 4;
    const float* ts0 = Tb + c * 1024;
    const float* tr0 = Tb + r * 1024 + 256;
    const float* ts1 = Tb + c * 1024 + 512;
    const float* tr1 = Tb + r * 1024 + 768;
    int swz = (c & 7) << 4;
    char* d0 = (char*)(hl[0]) + c * 512;
    char* d1 = (char*)(hl[1]) + c * 512;
#pragma unroll
    for (int kk = 0; kk < 16; ++kk) {
      int k = kq + kk * 16;
      f32x4 s0 = *(const f32x4*)(ts0 + k);
      f32x4 r0 = *(const f32x4*)(tr0 + k);
      f32x4 s1 = *(const f32x4*)(ts1 + k);
      f32x4 r1 = *(const f32x4*)(tr1 + k);
      uint32_t lo0 = (uint32_t)f2bf(fmaxf(s0[0] + r0[0], 0.f)) |
                     ((uint32_t)f2bf(fmaxf(s0[1] + r0[1], 0.f)) << 16);
      uint32_t hi0 = (uint32_t)f2bf(fmaxf(s0[2] + r0[2], 0.f)) |
                     ((uint32_t)f2bf(fmaxf(s0[3] + r0[3], 0.f)) << 16);
      uint32_t lo1 = (uint32_t)f2bf(fmaxf(s1[0] + r1[0], 0.f)) |
                     ((uint32_t)f2bf(fmaxf(s1[1] + r1[1], 0.f)) << 16);
      uint32_t hi1 = (uint32_t)f2bf(fmaxf(s1[2] + r1[2], 0.f)) |
                     ((uint32_t)f2bf(fmaxf(s1[3] + r1[3], 0.f)) << 16);
      int off = (k * 2) ^ swz;
      *(uint64_t*)(d0 + off) = (uint64_t)lo0 | ((uint64_t)hi0 << 32);
      *(uint64_t*)(d1 + off) = (uint64_t)lo1 | ((uint64_t)hi1 << 32);
    }
  }
  __syncthreads();

  int lane = t & 63;
  int w = t >> 6;            // wave id: owns N columns [w*32, w*32+32)
  int col = lane & 15;
  int khi = lane >> 4;
  f32x4 acc[2][4][2];
  const f32x4 z = {0.f, 0.f, 0.f, 0.f};
#pragma unroll
  for (int p = 0; p < 2; ++p)
#pragma unroll
    for (int mt = 0; mt < 4; ++mt)
#pragma unroll
      for (int nt = 0; nt < 2; ++nt) acc[p][mt][nt] = z;

  const uint16_t* w2a = W2bf;             // MLP0 weights [d][h]
  const uint16_t* w2b = W2bf + 32768;     // MLP1
#pragma unroll
  for (int ks = 0; ks < 8; ++ks) {
    int k0 = ks * 32 + khi * 8;
    bf16x8 a0[4], a1[4];
#pragma unroll
    for (int mt = 0; mt < 4; ++mt) {
      int cc = mt * 16 + col;
      int off = cc * 512 + ((k0 * 2) ^ ((cc & 7) << 4));
      a0[mt] = *(const bf16x8*)((const char*)(hl[0]) + off);
      a1[mt] = *(const bf16x8*)((const char*)(hl[1]) + off);
    }
    bf16x8 b0[2], b1v[2];
#pragma unroll
    for (int nt = 0; nt < 2; ++nt) {
      int n = w * 32 + nt * 16 + col;
      b0[nt]  = *(const bf16x8*)(const void*)(w2a + n * HH + k0);
      b1v[nt] = *(const bf16x8*)(const void*)(w2b + n * HH + k0);
    }
#pragma unroll
    for (int mt = 0; mt < 4; ++mt)
#pragma unroll
      for (int nt = 0; nt < 2; ++nt) {
        acc[0][mt][nt] = __builtin_amdgcn_mfma_f32_16x16x32_bf16(
            a0[mt], b0[nt], acc[0][mt][nt], 0, 0, 0);
        acc[1][mt][nt] = __builtin_amdgcn_mfma_f32_16x16x32_bf16(
            a1[mt], b1v[nt], acc[1][mt][nt], 0, 0, 0);
      }
  }

  // epilogue: bias, relu, arc blend, reduce over c (rows)
  int d0 = w * 32 + col;
  int d1 = d0 + 16;
  float bb0[2] = {b2_0[d0], b2_0[d1]};
  float bb1[2] = {b2_1[d0], b2_1[d1]};
  const int* arow = arcs + ((size_t)b * NN + r) * NN;
  float sum0 = 0.f, sum1 = 0.f;
#pragma unroll
  for (int mt = 0; mt < 4; ++mt) {
#pragma unroll
    for (int j = 0; j < 4; ++j) {
      int cc = mt * 16 + khi * 4 + j;
      float af = (float)arow[cc];   // 0 or 1
      {
        float m0 = fmaxf(acc[0][mt][0][j] + bb0[0], 0.f);
        float m1 = fmaxf(acc[1][mt][0][j] + bb1[0], 0.f);
        sum0 += m0 + af * (m1 - m0);
      }
      {
        float m0 = fmaxf(acc[0][mt][1][j] + bb0[1], 0.f);
        float m1 = fmaxf(acc[1][mt][1][j] + bb1[1], 0.f);
        sum1 += m0 + af * (m1 - m0);
      }
    }
  }
  sum0 += __shfl_xor(sum0, 16);
  sum0 += __shfl_xor(sum0, 32);
  sum1 += __shfl_xor(sum1, 16);
  sum1 += __shfl_xor(sum1, 32);
  if (lane < 16) {
    if (last) {
      size_t base = (size_t)b * NN * DD;   // row r=0
      out[b * DD + d0] = E[base + d0] + sum0;
      out[b * DD + d1] = E[base + d1] + sum1;
    } else {
      size_t base = ((size_t)b * NN + r) * DD;
      out[base + d0] = E[base + d0] + sum0;
      out[base + d1] = E[base + d1] + sum1;
    }
  }
}

extern "C" void kernel_launch(void* const* d_in, const int* in_sizes, int n_in,
                              void* d_out, int out_size, void* d_ws, size_t ws_size,
                              hipStream_t stream) {
  const int* x       = (const int*)d_in[0];
  const int* arcs    = (const int*)d_in[1];
  const float* table = (const float*)d_in[3];
  const float* W1_0  = (const float*)d_in[4];
  const float* b1_0  = (const float*)d_in[5];
  const float* W2_0  = (const float*)d_in[6];
  const float* b2_0  = (const float*)d_in[7];
  const float* W1_1  = (const float*)d_in[8];
  const float* b1_1  = (const float*)d_in[9];
  const float* W2_1  = (const float*)d_in[10];
  const float* b2_1  = (const float*)d_in[11];
  float* out = (float*)d_out;

  char* ws = (char*)d_ws;
  float* E        = (float*)ws;                                   // 1 MB
  float* Tall     = (float*)(ws + (1u << 20));                    // 8 MB
  float* Wt       = (float*)(ws + (9u << 20));                    // 512 KB
  uint16_t* W2bf  = (uint16_t*)(ws + (9u << 20) + (512u << 10));  // 128 KB

  k_gather<<<256, 256, 0, stream>>>(x, table, E);
  k_prep<<<256, 256, 0, stream>>>(W1_0, W1_1, W2_0, W2_1, Wt, W2bf);
  for (int l = 0; l < 3; ++l) {
    int last = (l == 2);
    k_T<<<256, 256, 0, stream>>>(E, Wt, b1_0, b1_1, Tall);
    dim3 grid(last ? 1 : NN, NB);
    k_edge<<<grid, 256, 0, stream>>>(Tall, arcs, E, last ? out : E,
                                     W2bf, b2_0, b2_1, last);
  }
}